// Round 1
// baseline (1104.902 us; speedup 1.0000x reference)
//
#include <hip/hip_runtime.h>
#include <stdint.h>

typedef unsigned short u16;
typedef unsigned int u32;
typedef __bf16 bf16x8 __attribute__((ext_vector_type(8)));
typedef float f32x4 __attribute__((ext_vector_type(4)));
typedef u16 u16x4 __attribute__((ext_vector_type(4)));
typedef u16 u16x8 __attribute__((ext_vector_type(8)));

#define MFMA16(a, b, c) __builtin_amdgcn_mfma_f32_16x16x32_bf16(a, b, c, 0, 0, 0)

__device__ __forceinline__ u16 f2bf(float f) {
  u32 u = __builtin_bit_cast(u32, f);
  u += 0x7FFFu + ((u >> 16) & 1u);
  return (u16)(u >> 16);
}

__device__ __forceinline__ bf16x8 ld16(const u16* p) {
  return __builtin_bit_cast(bf16x8, *(const uint4*)p);
}

// ---------------- weight conversion (once per launch) ----------------
__global__ __launch_bounds__(256) void convert_weights(
    const float* __restrict__ Wq, const float* __restrict__ Wk,
    const float* __restrict__ Wv, const float* __restrict__ fcw,
    u16* __restrict__ wq_b, u16* __restrict__ wk_b, u16* __restrict__ wv_b,
    u16* __restrict__ fcw_b) {
  int bx = blockIdx.x, tid = threadIdx.x;
  if (bx < 4096) {
    int i = (bx * 256 + tid) * 4;
    float4 f = *(const float4*)&fcw[i];
    u16x4 o = {f2bf(f.x), f2bf(f.y), f2bf(f.z), f2bf(f.w)};
    *(u16x4*)&fcw_b[i] = o;
  } else {
    int i = ((bx - 4096) * 256 + tid) * 4;
    const float sc = 0.022097086912079612f;  // 1/sqrt(2048) folded into Wq
    float4 q = *(const float4*)&Wq[i];
    u16x4 oq = {f2bf(q.x * sc), f2bf(q.y * sc), f2bf(q.z * sc), f2bf(q.w * sc)};
    *(u16x4*)&wq_b[i] = oq;
    float4 k = *(const float4*)&Wk[i];
    u16x4 ok = {f2bf(k.x), f2bf(k.y), f2bf(k.z), f2bf(k.w)};
    *(u16x4*)&wk_b[i] = ok;
    float4 v = *(const float4*)&Wv[i];
    u16x4 ov = {f2bf(v.x), f2bf(v.y), f2bf(v.z), f2bf(v.w)};
    *(u16x4*)&wv_b[i] = ov;
  }
}

// ---------------- QKV projection with gather ----------------
// Grid: (jt=8, h=16, n=8), 384 threads (6 waves).
// Token j (of 512) slot i channel c = src[n][(8j+i-b)&4095][c].
// Head h -> slot i0=h>>1, channels c0=(h&1)*128.  X tile: 64 tokens x 128 d.
// q = X @ (Wq*scale)^T ; k = X @ Wk^T ; v = X @ Wv^T.
// Q,K stored row-major [nh][512][128]; V stored transposed [nh][128][512].
__global__ __launch_bounds__(384) void qkv_kernel(
    const float* __restrict__ src, const u16* __restrict__ wq,
    const u16* __restrict__ wk, const u16* __restrict__ wvw,
    u16* __restrict__ Q, u16* __restrict__ K, u16* __restrict__ Vt, int bsh) {
  __shared__ u16 X[64 * 136];
  int jt = blockIdx.x, h = blockIdx.y, n = blockIdx.z;
  int tid = threadIdx.x;
  int i0 = h >> 1, c0 = (h & 1) * 128;
  // stage X tile (f32 -> bf16), 1024 chunks of 8 floats
  for (int it = 0; it < 3; ++it) {
    int c = tid + it * 384;
    if (c < 1024) {
      int row = c >> 4, seg = c & 15;
      int j = jt * 64 + row;
      int pos = (8 * j + i0 - bsh) & 4095;
      const float* g = src + ((size_t)n * 4096 + pos) * 256 + c0 + seg * 8;
      float4 f0 = *(const float4*)g;
      float4 f1 = *(const float4*)(g + 4);
      u16x8 v = {f2bf(f0.x), f2bf(f0.y), f2bf(f0.z), f2bf(f0.w),
                 f2bf(f1.x), f2bf(f1.y), f2bf(f1.z), f2bf(f1.w)};
      *(u16x8*)&X[row * 136 + seg * 8] = v;
    }
  }
  __syncthreads();
  int wv = tid >> 6, ln = tid & 63;
  int mat = wv >> 1;            // 0:q 1:k 2:v
  int cbase = (wv & 1) * 64;    // 64-col half
  const u16* W = (mat == 0) ? wq : (mat == 1) ? wk : wvw;
  int lr = ln & 15, lg = ln >> 4;
  f32x4 acc[4][4] = {};
#pragma unroll
  for (int kt = 0; kt < 4; ++kt) {
    bf16x8 a[4], b[4];
#pragma unroll
    for (int mt = 0; mt < 4; ++mt)
      a[mt] = ld16(&X[(mt * 16 + lr) * 136 + kt * 32 + lg * 8]);
#pragma unroll
    for (int nc = 0; nc < 4; ++nc)
      b[nc] = ld16(&W[(cbase + nc * 16 + lr) * 128 + kt * 32 + lg * 8]);
#pragma unroll
    for (int mt = 0; mt < 4; ++mt)
#pragma unroll
      for (int nc = 0; nc < 4; ++nc)
        acc[mt][nc] = MFMA16(a[mt], b[nc], acc[mt][nc]);
  }
  size_t nh = (size_t)(n * 16 + h);
  if (mat < 2) {
    u16* dst = (mat == 0 ? Q : K) + nh * 512 * 128;
#pragma unroll
    for (int mt = 0; mt < 4; ++mt)
#pragma unroll
      for (int nc = 0; nc < 4; ++nc) {
        int col = cbase + nc * 16 + lr;
        int jb = jt * 64 + mt * 16 + lg * 4;
#pragma unroll
        for (int r = 0; r < 4; ++r)
          dst[(size_t)(jb + r) * 128 + col] = f2bf(acc[mt][nc][r]);
      }
  } else {
    u16* dst = Vt + nh * 128 * 512;
#pragma unroll
    for (int mt = 0; mt < 4; ++mt)
#pragma unroll
      for (int nc = 0; nc < 4; ++nc) {
        int col = cbase + nc * 16 + lr;
        int jb = jt * 64 + mt * 16 + lg * 4;
        u16x4 pk = {f2bf(acc[mt][nc][0]), f2bf(acc[mt][nc][1]),
                    f2bf(acc[mt][nc][2]), f2bf(acc[mt][nc][3])};
        *(u16x4*)&dst[(size_t)col * 512 + jb] = pk;
      }
  }
}

// ---------------- flash attention over 512 tokens ----------------
// Grid: (qt=4, h=16, n=8), 256 threads (4 waves); wave owns 32 q-rows.
__global__ __launch_bounds__(256) void attn_kernel(
    const u16* __restrict__ Q, const u16* __restrict__ K,
    const u16* __restrict__ Vt, u16* __restrict__ O) {
  __shared__ u16 Kl[64 * 136];
  __shared__ u16 Vl[128 * 72];
  __shared__ u16 Pl[4 * 32 * 72];
  int qt = blockIdx.x, h = blockIdx.y, n = blockIdx.z;
  int tid = threadIdx.x, wv = tid >> 6, ln = tid & 63;
  int lr = ln & 15, lg = ln >> 4;
  size_t nh = (size_t)(n * 16 + h);
  const u16* Qb = Q + (nh * 512 + qt * 128 + wv * 32) * 128;
  const u16* Kb = K + nh * 512 * 128;
  const u16* Vb = Vt + nh * 128 * 512;
  u16* Pw = &Pl[wv * 32 * 72];
  bf16x8 qf[2][4];
#pragma unroll
  for (int mt = 0; mt < 2; ++mt)
#pragma unroll
    for (int kt = 0; kt < 4; ++kt)
      qf[mt][kt] = ld16(&Qb[(mt * 16 + lr) * 128 + kt * 32 + lg * 8]);
  f32x4 o[2][8] = {};
  float mrun[2][4], lrun[2][4];
#pragma unroll
  for (int mt = 0; mt < 2; ++mt)
#pragma unroll
    for (int r = 0; r < 4; ++r) { mrun[mt][r] = -1e30f; lrun[mt][r] = 0.f; }

  for (int kv = 0; kv < 8; ++kv) {
    // stage K tile 64x128 and Vt tile 128x64 (both bf16)
#pragma unroll
    for (int it = 0; it < 4; ++it) {
      int c = tid + it * 256;
      int row = c >> 4, seg = c & 15;
      *(uint4*)&Kl[row * 136 + seg * 8] =
          *(const uint4*)&Kb[(size_t)(kv * 64 + row) * 128 + seg * 8];
    }
#pragma unroll
    for (int it = 0; it < 4; ++it) {
      int c = tid + it * 256;
      int row = c >> 3, seg = c & 7;
      *(uint4*)&Vl[row * 72 + seg * 8] =
          *(const uint4*)&Vb[(size_t)row * 512 + kv * 64 + seg * 8];
    }
    __syncthreads();
    // S = Q K^T (scale folded into Wq)
    f32x4 s[2][4] = {};
#pragma unroll
    for (int nc = 0; nc < 4; ++nc) {
      bf16x8 bk[4];
#pragma unroll
      for (int kt = 0; kt < 4; ++kt)
        bk[kt] = ld16(&Kl[(nc * 16 + lr) * 136 + kt * 32 + lg * 8]);
#pragma unroll
      for (int mt = 0; mt < 2; ++mt)
#pragma unroll
        for (int kt = 0; kt < 4; ++kt)
          s[mt][nc] = MFMA16(qf[mt][kt], bk[kt], s[mt][nc]);
    }
    // online softmax
    float al[2][4];
#pragma unroll
    for (int mt = 0; mt < 2; ++mt)
#pragma unroll
      for (int r = 0; r < 4; ++r) {
        float pm = fmaxf(fmaxf(s[mt][0][r], s[mt][1][r]),
                         fmaxf(s[mt][2][r], s[mt][3][r]));
#pragma unroll
        for (int d = 1; d < 16; d <<= 1) pm = fmaxf(pm, __shfl_xor(pm, d));
        float nm = fmaxf(mrun[mt][r], pm);
        al[mt][r] = __expf(mrun[mt][r] - nm);
        mrun[mt][r] = nm;
        float rs = 0.f;
#pragma unroll
        for (int nc = 0; nc < 4; ++nc) {
          float e = __expf(s[mt][nc][r] - nm);
          s[mt][nc][r] = e;
          rs += e;
        }
#pragma unroll
        for (int d = 1; d < 16; d <<= 1) rs += __shfl_xor(rs, d);
        lrun[mt][r] = lrun[mt][r] * al[mt][r] + rs;
      }
    // P -> per-wave LDS (relayout D-frag -> A-frag)
#pragma unroll
    for (int mt = 0; mt < 2; ++mt)
#pragma unroll
      for (int nc = 0; nc < 4; ++nc)
#pragma unroll
        for (int r = 0; r < 4; ++r)
          Pw[(mt * 16 + lg * 4 + r) * 72 + nc * 16 + lr] = f2bf(s[mt][nc][r]);
    // rescale O
#pragma unroll
    for (int mt = 0; mt < 2; ++mt)
#pragma unroll
      for (int n2 = 0; n2 < 8; ++n2)
#pragma unroll
        for (int r = 0; r < 4; ++r) o[mt][n2][r] *= al[mt][r];
    // O += P @ V
    bf16x8 pa[2][2];
#pragma unroll
    for (int mt = 0; mt < 2; ++mt)
#pragma unroll
      for (int k2 = 0; k2 < 2; ++k2)
        pa[mt][k2] = ld16(&Pw[(mt * 16 + lr) * 72 + k2 * 32 + lg * 8]);
#pragma unroll
    for (int n2 = 0; n2 < 8; ++n2) {
      bf16x8 bv[2];
#pragma unroll
      for (int k2 = 0; k2 < 2; ++k2)
        bv[k2] = ld16(&Vl[(n2 * 16 + lr) * 72 + k2 * 32 + lg * 8]);
#pragma unroll
      for (int mt = 0; mt < 2; ++mt)
#pragma unroll
        for (int k2 = 0; k2 < 2; ++k2)
          o[mt][n2] = MFMA16(pa[mt][k2], bv[k2], o[mt][n2]);
    }
    __syncthreads();
  }
  // normalize + write attn_out [n*512+j][2048]
#pragma unroll
  for (int mt = 0; mt < 2; ++mt)
#pragma unroll
    for (int r = 0; r < 4; ++r) {
      float inv = 1.f / lrun[mt][r];
      int row = qt * 128 + wv * 32 + mt * 16 + lg * 4 + r;
      u16* dst = O + ((size_t)n * 512 + row) * 2048 + h * 128;
#pragma unroll
      for (int n2 = 0; n2 < 8; ++n2)
        dst[n2 * 16 + lr] = f2bf(o[mt][n2][r] * inv);
    }
}

// ---------------- FC GEMM + bias + permuted scatter ----------------
// C[row=(n,j)][e] = sum_k A[row][k] fc_w[e][k] + fc_b[e]
// -> dout[n][(8j + (e>>8) - b) & 4095][e & 255]
// Grid: (bn=16, bm=32), 256 threads, m97-style 128x128 tile, BK=32.
__global__ __launch_bounds__(256) void fc_kernel(
    const u16* __restrict__ A, const u16* __restrict__ Bw,
    const float* __restrict__ bias, float* __restrict__ dout, int bsh) {
  __shared__ u16 Al[128 * 32];
  __shared__ u16 Bl[128 * 32];
  int bn = blockIdx.x, bm = blockIdx.y;
  int tid = threadIdx.x, wv = tid >> 6, ln = tid & 63;
  int lr = ln & 15, lg = ln >> 4;
  int R0 = bm * 128, C0 = bn * 128;
  int wr = (wv & 1) * 64, wc = (wv >> 1) * 64;
  int lrow = ln >> 2, lseg = ln & 3;
  f32x4 acc[4][4] = {};
  for (int ks = 0; ks < 64; ++ks) {
    int k0 = ks * 32;
#pragma unroll
    for (int ch = wv; ch < 8; ch += 4) {
      const u16* ga = A + (size_t)(R0 + ch * 16 + lrow) * 2048 + k0 + lseg * 8;
      __builtin_amdgcn_global_load_lds(
          (const __attribute__((address_space(1))) u32*)ga,
          (__attribute__((address_space(3))) u32*)&Al[ch * 512], 16, 0, 0);
      const u16* gb = Bw + (size_t)(C0 + ch * 16 + lrow) * 2048 + k0 + lseg * 8;
      __builtin_amdgcn_global_load_lds(
          (const __attribute__((address_space(1))) u32*)gb,
          (__attribute__((address_space(3))) u32*)&Bl[ch * 512], 16, 0, 0);
    }
    __syncthreads();
    bf16x8 a[4], b[4];
#pragma unroll
    for (int mt = 0; mt < 4; ++mt)
      a[mt] = ld16(&Al[(wr + mt * 16 + lr) * 32 + lg * 8]);
#pragma unroll
    for (int nc = 0; nc < 4; ++nc)
      b[nc] = ld16(&Bl[(wc + nc * 16 + lr) * 32 + lg * 8]);
#pragma unroll
    for (int mt = 0; mt < 4; ++mt)
#pragma unroll
      for (int nc = 0; nc < 4; ++nc)
        acc[mt][nc] = MFMA16(a[mt], b[nc], acc[mt][nc]);
    __syncthreads();
  }
#pragma unroll
  for (int nc = 0; nc < 4; ++nc) {
    int e = C0 + wc + nc * 16 + lr;
    float bv = bias[e];
    int i = e >> 8, cc = e & 255;
#pragma unroll
    for (int mt = 0; mt < 4; ++mt)
#pragma unroll
      for (int r = 0; r < 4; ++r) {
        int row = R0 + wr + mt * 16 + lg * 4 + r;
        int nn = row >> 9, j = row & 511;
        int pos = (8 * j + i - bsh) & 4095;
        dout[((size_t)nn * 4096 + pos) * 256 + cc] = acc[mt][nc][r] + bv;
      }
  }
}

extern "C" void kernel_launch(void* const* d_in, const int* in_sizes, int n_in,
                              void* d_out, int out_size, void* d_ws, size_t ws_size,
                              hipStream_t stream) {
  const float* M = (const float*)d_in[0];
  const float* Wq = (const float*)d_in[1];
  const float* Wk = (const float*)d_in[2];
  const float* Wv = (const float*)d_in[3];
  const float* fcw = (const float*)d_in[4];
  const float* fcb = (const float*)d_in[5];
  float* out = (float*)d_out;
  char* ws = (char*)d_ws;
  u16* wq_b = (u16*)(ws + (0 << 10));
  u16* wk_b = (u16*)(ws + (32 << 10));
  u16* wv_b = (u16*)(ws + (64 << 10));
  u16* fcw_b = (u16*)(ws + (128 << 10));
  u16* Qb = (u16*)(ws + ((size_t)16 << 20));
  u16* Kb = (u16*)(ws + ((size_t)32 << 20));
  u16* Vtb = (u16*)(ws + ((size_t)48 << 20));
  u16* Ab = (u16*)(ws + ((size_t)64 << 20));

  convert_weights<<<4112, 256, 0, stream>>>(Wq, Wk, Wv, fcw, wq_b, wk_b, wv_b, fcw_b);
  for (int b = 0; b < 8; ++b) {
    const float* src = (b == 0) ? M : out;
    qkv_kernel<<<dim3(8, 16, 8), 384, 0, stream>>>(src, wq_b, wk_b, wv_b, Qb, Kb, Vtb, b);
    attn_kernel<<<dim3(4, 16, 8), 256, 0, stream>>>(Qb, Kb, Vtb, Ab);
    fc_kernel<<<dim3(16, 32), 256, 0, stream>>>(Ab, fcw_b, fcb, out, b);
  }
}